// Round 9
// baseline (210.480 us; speedup 1.0000x reference)
//
#include <hip/hip_runtime.h>

// CARAFE fused: N=8, C=256, H=W=64, UP=2, K=3 -> out (8,256,128,128) fp32
// One block per (n, row), 512 threads (8 waves), LDS = 16 KB (y/ws exchange only).
// Layer0: x from global (vmcnt), weights via wave-uniform SGPR loads (lgkmcnt) --
//         independent counters overlap (r4-vs-r7 lesson: never mix ds_read+s_load).
// Phase 2: 3 row loads per channel; w+-1 column taps reconstructed with
//          __shfl_up/down (W=64 == wave width; pad masks handle edges).

#define EPS_BN 1e-5f

__global__ __launch_bounds__(512, 4) void carafe_fused(
    const float* __restrict__ x,
    const float* __restrict__ w0, const float* __restrict__ b0,
    const float* __restrict__ g0, const float* __restrict__ be0,
    const float* __restrict__ m0, const float* __restrict__ v0,
    const float* __restrict__ w1, const float* __restrict__ b1,
    const float* __restrict__ g1, const float* __restrict__ be1,
    const float* __restrict__ m1, const float* __restrict__ v1,
    float* __restrict__ out)
{
    __shared__ float ys[64 * 64];   // [o][w] 16 KB; reused as ws[36][64] later

    const int tid = threadIdx.x;
    const int n   = blockIdx.x >> 6;     // 0..7
    const int hh  = blockIdx.x & 63;     // row
    const int w   = tid & 63;            // pixel col (lane)
    const int og  = __builtin_amdgcn_readfirstlane(tid >> 6);  // wave id 0..7

    // ---- layer0: y[o][w], o = og*8 + j. x global (vmcnt), weights SGPR (lgkmcnt). ----
    float acc[8];
#pragma unroll
    for (int j = 0; j < 8; ++j) acc[j] = 0.f;

    const float* xp  = x + n * 1048576 + hh * 64 + w;   // + c*4096 per channel
    const float* w0p = w0 + og * 8 * 256;               // wave-uniform base

#pragma unroll 8
    for (int c = 0; c < 256; ++c) {
        const float xv = xp[c * 4096];
#pragma unroll
        for (int j = 0; j < 8; ++j)
            acc[j] = fmaf(xv, w0p[j * 256 + c], acc[j]);
    }

    // BN0 + ReLU -> ys
#pragma unroll
    for (int j = 0; j < 8; ++j) {
        const int o = og * 8 + j;
        const float sc = g0[o] * rsqrtf(v0[o] + EPS_BN);
        const float sh = (b0[o] - m0[o]) * sc + be0[o];
        ys[o * 64 + w] = fmaxf(fmaf(acc[j], sc, sh), 0.f);
    }
    __syncthreads();

    // ---- layer1: enc[p][w], p = kk*4 + u, u = og&3 (waves 4-7 duplicate 0-3). ----
    float e9[9];
#pragma unroll
    for (int kk = 0; kk < 9; ++kk) e9[kk] = 0.f;
    const int u = og & 3;
    const float* w1p = w1 + u * 64;          // w1[(kk*4+u)*64 + o] = w1p[kk*256 + o]
#pragma unroll 8
    for (int o = 0; o < 64; ++o) {
        const float yv = ys[o * 64 + w];
#pragma unroll
        for (int kk = 0; kk < 9; ++kk)
            e9[kk] = fmaf(yv, w1p[kk * 256 + o], e9[kk]);
    }

    // BN1 + ReLU, softmax over kk (in-register)
    float mx = -1e30f;
#pragma unroll
    for (int kk = 0; kk < 9; ++kk) {
        const int p = kk * 4 + u;
        const float sc = g1[p] * rsqrtf(v1[p] + EPS_BN);
        const float sh = (b1[p] - m1[p]) * sc + be1[p];
        float e = fmaxf(fmaf(e9[kk], sc, sh), 0.f);
        e9[kk] = e;
        mx = fmaxf(mx, e);
    }
    float s = 0.f;
#pragma unroll
    for (int kk = 0; kk < 9; ++kk) {
        e9[kk] = __expf(e9[kk] - mx);
        s += e9[kk];
    }
    const float inv = 1.f / s;

    __syncthreads();                 // all ys reads done; safe to overwrite as ws
    if (og < 4) {
#pragma unroll
        for (int kk = 0; kk < 9; ++kk)
            ys[(kk * 4 + u) * 64 + w] = e9[kk] * inv;   // ws[p][w]
    }
    __syncthreads();

    // ---- phase 2: reassemble row hh; wave og handles channels og*32 .. og*32+31 ----
    float wt[36];
#pragma unroll
    for (int p = 0; p < 36; ++p) wt[p] = ys[p * 64 + w];   // 2 lanes/bank: free

    const bool hm = (hh > 0), hp = (hh < 63);
    const bool wm = (w > 0),  wp = (w < 63);
    const float* xrow = x + n * 1048576 + hh * 64;   // (n, c=0, hh, 0)

#pragma unroll 4
    for (int i = 0; i < 32; ++i) {
        const int cc = og * 32 + i;
        const float* xr = xrow + cc * 4096;          // row hh of channel cc

        // 3 row loads (own column only); L2-hot for row hh (layer0 just read it)
        const float xm1 = hm ? xr[w - 64] : 0.f;     // (hh-1, w)
        const float x01 = xr[w];                     // (hh  , w)
        const float xp1 = hp ? xr[w + 64] : 0.f;     // (hh+1, w)

        // column neighbors via cross-lane shift (wave width 64 == W)
        float xm0 = __shfl_up  (xm1, 1); xm0 = wm ? xm0 : 0.f;
        float xm2 = __shfl_down(xm1, 1); xm2 = wp ? xm2 : 0.f;
        float x00 = __shfl_up  (x01, 1); x00 = wm ? x00 : 0.f;
        float x02 = __shfl_down(x01, 1); x02 = wp ? x02 : 0.f;
        float xp0 = __shfl_up  (xp1, 1); xp0 = wm ? xp0 : 0.f;
        float xp2 = __shfl_down(xp1, 1); xp2 = wp ? xp2 : 0.f;

        float a0, a1, a2, a3;  // u = 0..3
        a0 = fmaf(xm0, wt[0],  fmaf(xm1, wt[4],  xm2 * wt[8]));
        a1 = fmaf(xm0, wt[1],  fmaf(xm1, wt[5],  xm2 * wt[9]));
        a2 = fmaf(xm0, wt[2],  fmaf(xm1, wt[6],  xm2 * wt[10]));
        a3 = fmaf(xm0, wt[3],  fmaf(xm1, wt[7],  xm2 * wt[11]));

        a0 = fmaf(x00, wt[12], fmaf(x01, wt[16], fmaf(x02, wt[20], a0)));
        a1 = fmaf(x00, wt[13], fmaf(x01, wt[17], fmaf(x02, wt[21], a1)));
        a2 = fmaf(x00, wt[14], fmaf(x01, wt[18], fmaf(x02, wt[22], a2)));
        a3 = fmaf(x00, wt[15], fmaf(x01, wt[19], fmaf(x02, wt[23], a3)));

        a0 = fmaf(xp0, wt[24], fmaf(xp1, wt[28], fmaf(xp2, wt[32], a0)));
        a1 = fmaf(xp0, wt[25], fmaf(xp1, wt[29], fmaf(xp2, wt[33], a1)));
        a2 = fmaf(xp0, wt[26], fmaf(xp1, wt[30], fmaf(xp2, wt[34], a2)));
        a3 = fmaf(xp0, wt[27], fmaf(xp1, wt[31], fmaf(xp2, wt[35], a3)));

        float* op = out + ((n * 256 + cc) * 128 + 2 * hh) * 128 + 2 * w;
        float2 r0; r0.x = a0; r0.y = a1;   // row 2h   : (u=0,u=1)
        float2 r1; r1.x = a2; r1.y = a3;   // row 2h+1 : (u=2,u=3)
        *reinterpret_cast<float2*>(op)       = r0;   // 512 B contiguous per wave
        *reinterpret_cast<float2*>(op + 128) = r1;
    }
}

extern "C" void kernel_launch(void* const* d_in, const int* in_sizes, int n_in,
                              void* d_out, int out_size, void* d_ws, size_t ws_size,
                              hipStream_t stream)
{
    const float* x   = (const float*)d_in[0];
    const float* w0  = (const float*)d_in[1];
    const float* b0  = (const float*)d_in[2];
    const float* g0  = (const float*)d_in[3];
    const float* be0 = (const float*)d_in[4];
    const float* m0  = (const float*)d_in[5];
    const float* v0  = (const float*)d_in[6];
    const float* w1  = (const float*)d_in[7];
    const float* b1  = (const float*)d_in[8];
    const float* g1  = (const float*)d_in[9];
    const float* be1 = (const float*)d_in[10];
    const float* m1  = (const float*)d_in[11];
    const float* v1  = (const float*)d_in[12];

    float* out = (float*)d_out;

    // 512 blocks (n x row) x 512 threads; 16 KB LDS -> 2 blocks/CU, 16 waves/CU.
    hipLaunchKernelGGL(carafe_fused, dim3(512), dim3(512), 0, stream,
                       x, w0, b0, g0, be0, m0, v0, w1, b1, g1, be1, m1, v1, out);
}